// Round 5
// baseline (763.338 us; speedup 1.0000x reference)
//
#include <hip/hip_runtime.h>

#define N_ 20000
#define E_ 100000

typedef __attribute__((ext_vector_type(8))) short short8;
typedef __attribute__((ext_vector_type(4))) float f32x4;

__device__ __forceinline__ unsigned short f2bf(float f) {
  union { float f; unsigned u; } v; v.f = f;
  unsigned r = v.u + 0x7fffu + ((v.u >> 16) & 1u);
  return (unsigned short)(r >> 16);
}
__device__ __forceinline__ float bf2f(unsigned short h) {
  union { unsigned u; float f; } v; v.u = ((unsigned)h) << 16;
  return v.f;
}
__device__ __forceinline__ short8 pack8(float4 a, float4 b) {
  short8 v;
  v[0] = (short)f2bf(a.x); v[1] = (short)f2bf(a.y);
  v[2] = (short)f2bf(a.z); v[3] = (short)f2bf(a.w);
  v[4] = (short)f2bf(b.x); v[5] = (short)f2bf(b.y);
  v[6] = (short)f2bf(b.z); v[7] = (short)f2bf(b.w);
  return v;
}

// ---------------- K1: h2 = relu(edge_attr @ e1_w.T + e1_b), bf16 [E][128], via MFMA
__global__ __launch_bounds__(256) void k_h2(const float* __restrict__ ea,
                                            const float* __restrict__ e1w,
                                            const float* __restrict__ e1b,
                                            unsigned short* __restrict__ h2) {
  int t = threadIdx.x, w = t >> 6, l = t & 63, g = l >> 4, lm = l & 15;
  short8 bf[8];
#pragma unroll
  for (int cf = 0; cf < 8; ++cf) {
    int c = cf * 16 + lm;
    short8 v = {0, 0, 0, 0, 0, 0, 0, 0};
    if (g < 2) {
      const float4* wp = (const float4*)(e1w + c * 16 + g * 8);
      v = pack8(wp[0], wp[1]);
    } else if (g == 2) {
      v[0] = (short)f2bf(e1b[c]);
    }
    bf[cf] = v;
  }
  const f32x4 z = {0.f, 0.f, 0.f, 0.f};
  for (int tile = 0; tile < 4; ++tile) {
    int e0 = blockIdx.x * 256 + tile * 64 + w * 16;
    if (e0 >= E_) break;
    int er = e0 + lm; if (er >= E_) er = E_ - 1;
    short8 a = {0, 0, 0, 0, 0, 0, 0, 0};
    if (g < 2) {
      const float4* ap = (const float4*)(ea + er * 16 + g * 8);
      a = pack8(ap[0], ap[1]);
    } else if (g == 2) {
      a[0] = (short)0x3F80;  // bf16(1.0)
    }
#pragma unroll
    for (int cf = 0; cf < 8; ++cf) {
      f32x4 acc = __builtin_amdgcn_mfma_f32_16x16x32_bf16(a, bf[cf], z, 0, 0, 0);
#pragma unroll
      for (int r = 0; r < 4; ++r) {
        int e = e0 + g * 4 + r;
        if (e < E_) h2[(size_t)e * 128 + cf * 16 + lm] = f2bf(fmaxf(acc[r], 0.f));
      }
    }
  }
}

// ---------------- K2: pre-swizzle e2_w into chunk-contiguous MFMA A-frag order
// Af[((ct*4 + kf)*64 + l)*8 + r] = bf16(e2w[(ct*16+(l&15))*128 + kf*32 + (l>>4)*8 + r])
__global__ __launch_bounds__(256) void k_prep_bf(const float* __restrict__ e2w,
                                                 unsigned short* __restrict__ Af) {
  int tid = blockIdx.x * 256 + threadIdx.x;  // 65536 threads
  int l = tid & 63, kf = (tid >> 6) & 3, ct = tid >> 8;
  int gq = l >> 4, lm = l & 15;
  const float* src = e2w + (ct * 16 + lm) * 128 + kf * 32 + gq * 8;
  short8 v = pack8(*(const float4*)src, *(const float4*)(src + 4));
  *(short8*)((short*)Af + (size_t)tid * 8) = v;
}

// ---------------- K3: out0 = relu(nf @ mp_w.T + mp_b); y0 = out0 @ e2bmat
// 64 nodes/block
__global__ __launch_bounds__(256) void k_node_in(const float* __restrict__ nfm,
                                                 const float* __restrict__ mpw,
                                                 const float* __restrict__ mpb,
                                                 const float* __restrict__ e2b,
                                                 float* __restrict__ outc,
                                                 float* __restrict__ yc) {
  __shared__ float wT[64 * 65];
  __shared__ float xr[4 * 65];
  __shared__ float nr[4 * 65];
  int t = threadIdx.x;
  for (int idx = t; idx < 4096; idx += 256) {
    int o = idx >> 6, i = idx & 63;
    wT[i * 65 + o] = mpw[idx];
  }
  __syncthreads();
  int nl = t >> 6, o = t & 63;
  for (int it = 0; it < 16; ++it) {
    int n = blockIdx.x * 64 + it * 4 + nl;
    bool ok = n < N_;
    int nc = ok ? n : N_ - 1;
    xr[nl * 65 + o] = nfm[(size_t)nc * 64 + o];
    __syncthreads();
    float acc = mpb[o];
#pragma unroll 8
    for (int i = 0; i < 64; ++i) acc += xr[nl * 65 + i] * wT[i * 65 + o];
    float m = fmaxf(acc, 0.f);
    if (ok) outc[(size_t)n * 64 + o] = m;
    nr[nl * 65 + o] = m;
    __syncthreads();
    float yv = 0.f;
#pragma unroll 8
    for (int j = 0; j < 64; ++j) yv += nr[nl * 65 + j] * e2b[j * 64 + o];
    if (ok) yc[(size_t)n * 64 + o] = yv;
    __syncthreads();
  }
}

// ---------------- zero kernel (once; k_update re-zeroes thereafter)
__global__ void k_zero(float* __restrict__ p, int n) {
  int i = blockIdx.x * 256 + threadIdx.x;
  if (i < n) p[i] = 0.f;
}

// ---------------- K5: fused msgs + scatter. 128 edges/block, 256 threads, 4 waves.
// wave w = (op, kh): op=w>>1 owns oq {2op,2op+1}; kh=w&1 owns kf {2kh,2kh+1}.
// Each W-frag read by exactly ONE wave (no duplication); W streamed once per block.
// hf (h2 frags, all 128 edges x 2 kf) resident in VGPRs; kh-partials reduced via LDS.
__global__ __launch_bounds__(256, 3) void k_msgs(const float* __restrict__ x,
                                                 const float* __restrict__ y,
                                                 const unsigned short* __restrict__ h2,
                                                 const unsigned short* __restrict__ Af,
                                                 const int* __restrict__ ei,
                                                 float* __restrict__ agg) {
  __shared__ __align__(16) unsigned char POOL[33792];  // xg f32[64][132] | pm u16[2][128][66]
  __shared__ int sidx[128];
  __shared__ int didx[128];
  int t = threadIdx.x, w = t >> 6, l = t & 63;
  int op = w >> 1, kh = w & 1;
  int gq = l >> 4, lm = l & 15;
  int e0 = blockIdx.x * 128;
  if (t < 128) {
    int e = e0 + t;
    sidx[t] = (e < E_) ? ei[e] : 0;
    didx[t] = (e < E_) ? ei[E_ + e] : -1;
  }
  __syncthreads();  // sidx ready
  // hf: h2 frags for all 128 edges, this wave's 2 kf's
  int kb = 2 * kh;
  short8 hf[8][2];
#pragma unroll
  for (int ef = 0; ef < 8; ++ef) {
    int e = e0 + ef * 16 + lm;
    if (e >= E_) e = E_ - 1;
    const short8* hp = (const short8*)(h2 + (size_t)e * 128 + gq * 8);
    hf[ef][0] = hp[(kb + 0) * 4];
    hf[ef][1] = hp[(kb + 1) * 4];
  }
  // xg gather: f32 x^T [i][e], stride 132
  float* xg = (float*)POOL;
  {
    int e = t >> 1, h = t & 1;
    const float* xr = x + (size_t)sidx[e] * 64 + h * 32;
#pragma unroll
    for (int q = 0; q < 8; ++q) {
      float4 v = *(const float4*)(xr + q * 4);
      int ib = h * 32 + q * 4;
      xg[(ib + 0) * 132 + e] = v.x;
      xg[(ib + 1) * 132 + e] = v.y;
      xg[(ib + 2) * 132 + e] = v.z;
      xg[(ib + 3) * 132 + e] = v.w;
    }
  }
  __syncthreads();  // xg ready

  f32x4 macc[8][2];  // [ef][oql]
#pragma unroll
  for (int ef = 0; ef < 8; ++ef) {
    macc[ef][0] = f32x4{0.f, 0.f, 0.f, 0.f};
    macc[ef][1] = f32x4{0.f, 0.f, 0.f, 0.f};
  }
  const f32x4 z = {0.f, 0.f, 0.f, 0.f};
  const short8* As = (const short8*)Af;
  int fb = 2 * op;

  for (int i = 0; i < 64; ++i) {
    int ct0 = i * 4 + fb;
    const short8* p0 = As + (size_t)(ct0 * 4 + kb) * 64 + l;
    short8 w00 = p0[0];    // (oq0, kf0)
    short8 w01 = p0[64];   // (oq0, kf1)
    short8 w10 = p0[256];  // (oq1, kf0)
    short8 w11 = p0[320];  // (oq1, kf1)
#pragma unroll
    for (int ef = 0; ef < 8; ++ef) {
      float xs = xg[i * 132 + ef * 16 + lm];
      f32x4 d0, d1;
      d0 = __builtin_amdgcn_mfma_f32_16x16x32_bf16(w00, hf[ef][0], z, 0, 0, 0);
      d1 = __builtin_amdgcn_mfma_f32_16x16x32_bf16(w10, hf[ef][0], z, 0, 0, 0);
      d0 = __builtin_amdgcn_mfma_f32_16x16x32_bf16(w01, hf[ef][1], d0, 0, 0, 0);
      d1 = __builtin_amdgcn_mfma_f32_16x16x32_bf16(w11, hf[ef][1], d1, 0, 0, 0);
      macc[ef][0] += xs * d0;
      macc[ef][1] += xs * d1;
    }
  }
  __syncthreads();  // all waves done reading xg; POOL re-used as pm
  // pm: u16 [kh][e][o] stride 66; wave writes its (kh; o-range op*32..op*32+32)
  unsigned short* pm = (unsigned short*)POOL;
#pragma unroll
  for (int ef = 0; ef < 8; ++ef)
#pragma unroll
    for (int oql = 0; oql < 2; ++oql)
#pragma unroll
      for (int r = 0; r < 4; ++r)
        pm[kh * 8448 + (ef * 16 + lm) * 66 + op * 32 + oql * 16 + gq * 4 + r] =
            f2bf(macc[ef][oql][r]);
  __syncthreads();
  // reduce kh pairs + e2_b rank-1 term (y[src]) + scatter-add
  for (int it = 0; it < 32; ++it) {
    int idx = it * 256 + t;
    int e = idx >> 6, o = idx & 63;
    int d = didx[e];
    if (d >= 0) {
      float v = bf2f(pm[e * 66 + o]) + bf2f(pm[8448 + e * 66 + o]);
      v += y[(size_t)sidx[e] * 64 + o];
      atomicAdd(agg + (size_t)d * 64 + o, v);
    }
  }
}

// ---------------- K6: node update (+ re-zero agg for next step), 64 nodes/block
__global__ __launch_bounds__(256) void k_update(const float* __restrict__ outc,
                                                float* __restrict__ agg,
                                                const float* __restrict__ root,
                                                const float* __restrict__ convb,
                                                const float* __restrict__ msgw,
                                                const float* __restrict__ msgb,
                                                const float* __restrict__ e2b,
                                                const float* __restrict__ nfm,
                                                int last,
                                                float* __restrict__ outn,
                                                float* __restrict__ yn,
                                                float* __restrict__ dout) {
  __shared__ float wT[128 * 65];
  __shared__ float xr[4 * 65];
  __shared__ float mr[4 * 65];
  __shared__ float nr[4 * 65];
  int t = threadIdx.x;
  for (int idx = t; idx < 8192; idx += 256) {
    int o = idx >> 7, j = idx & 127;
    wT[j * 65 + o] = msgw[idx];
  }
  __syncthreads();
  int nl = t >> 6, o = t & 63;
  for (int it = 0; it < 16; ++it) {
    int n = blockIdx.x * 64 + it * 4 + nl;
    bool ok = n < N_;
    int nc = ok ? n : N_ - 1;
    xr[nl * 65 + o] = outc[(size_t)nc * 64 + o];
    __syncthreads();
    float acc = agg[(size_t)nc * 64 + o] + convb[o];
    if (ok) agg[(size_t)n * 64 + o] = 0.f;
#pragma unroll 8
    for (int i = 0; i < 64; ++i) acc += xr[nl * 65 + i] * root[i * 64 + o];
    float m = fmaxf(acc, 0.f);
    mr[nl * 65 + o] = m;
    __syncthreads();
    float o2 = msgb[o];
#pragma unroll 8
    for (int j = 0; j < 64; ++j)
      o2 += mr[nl * 65 + j] * wT[j * 65 + o] + xr[nl * 65 + j] * wT[(64 + j) * 65 + o];
    nr[nl * 65 + o] = o2;
    __syncthreads();
    if (last) {
      if (ok) dout[(size_t)n * 64 + o] = o2 + nfm[(size_t)n * 64 + o];
    } else {
      float yv = 0.f;
#pragma unroll 8
      for (int j = 0; j < 64; ++j) yv += nr[nl * 65 + j] * e2b[j * 64 + o];
      if (ok) {
        outn[(size_t)n * 64 + o] = o2;
        yn[(size_t)n * 64 + o] = yv;
      }
    }
    __syncthreads();
  }
}

extern "C" void kernel_launch(void* const* d_in, const int* in_sizes, int n_in,
                              void* d_out, int out_size, void* d_ws, size_t ws_size,
                              hipStream_t stream) {
  const float* nfm  = (const float*)d_in[0];
  const float* ea   = (const float*)d_in[1];
  const int*   ei   = (const int*)d_in[2];
  const float* mpw  = (const float*)d_in[3];
  const float* mpb  = (const float*)d_in[4];
  const float* msgw = (const float*)d_in[5];
  const float* msgb = (const float*)d_in[6];
  const float* e1w  = (const float*)d_in[7];
  const float* e1b  = (const float*)d_in[8];
  const float* e2w  = (const float*)d_in[9];
  const float* e2b  = (const float*)d_in[10];
  const float* root = (const float*)d_in[11];
  const float* convb= (const float*)d_in[12];
  float* out = (float*)d_out;

  char* ws = (char*)d_ws;
  unsigned short* h2 = (unsigned short*)ws; ws += (size_t)E_ * 128 * 2;
  unsigned short* Af = (unsigned short*)ws; ws += (size_t)4096 * 128 * 2;
  float* outa = (float*)ws; ws += (size_t)N_ * 64 * 4;
  float* ya   = (float*)ws; ws += (size_t)N_ * 64 * 4;
  float* outb = (float*)ws; ws += (size_t)N_ * 64 * 4;
  float* yb   = (float*)ws; ws += (size_t)N_ * 64 * 4;
  float* agg  = (float*)ws; ws += (size_t)N_ * 64 * 4;

  hipLaunchKernelGGL(k_prep_bf, dim3(256), dim3(256), 0, stream, e2w, Af);
  hipLaunchKernelGGL(k_zero, dim3((N_ * 64 + 255) / 256), dim3(256), 0, stream, agg, N_ * 64);
  hipLaunchKernelGGL(k_h2, dim3((E_ + 255) / 256), dim3(256), 0, stream, ea, e1w, e1b, h2);
  hipLaunchKernelGGL(k_node_in, dim3((N_ + 63) / 64), dim3(256), 0, stream, nfm, mpw, mpb, e2b, outa, ya);

  float* oc = outa; float* yc = ya; float* on = outb; float* yv = yb;
  for (int s = 0; s < 3; ++s) {
    hipLaunchKernelGGL(k_msgs, dim3((E_ + 127) / 128), dim3(256), 0, stream, oc, yc, h2, Af, ei, agg);
    hipLaunchKernelGGL(k_update, dim3((N_ + 63) / 64), dim3(256), 0, stream, oc, agg, root, convb,
                       msgw, msgb, e2b, nfm, (s == 2) ? 1 : 0, on, yv, out);
    float* tp;
    tp = oc; oc = on; on = tp;
    tp = yc; yc = yv; yv = tp;
  }
}

// Round 8
// 762.147 us; speedup vs baseline: 1.0016x; 1.0016x over previous
//
#include <hip/hip_runtime.h>

#define N_ 20000
#define E_ 100000

typedef __attribute__((ext_vector_type(8))) short short8;
typedef __attribute__((ext_vector_type(4))) float f32x4;

__device__ __forceinline__ unsigned short f2bf(float f) {
  union { float f; unsigned u; } v; v.f = f;
  unsigned r = v.u + 0x7fffu + ((v.u >> 16) & 1u);
  return (unsigned short)(r >> 16);
}
__device__ __forceinline__ float bf2f(unsigned short h) {
  union { unsigned u; float f; } v; v.u = ((unsigned)h) << 16;
  return v.f;
}
__device__ __forceinline__ short8 pack8(float4 a, float4 b) {
  short8 v;
  v[0] = (short)f2bf(a.x); v[1] = (short)f2bf(a.y);
  v[2] = (short)f2bf(a.z); v[3] = (short)f2bf(a.w);
  v[4] = (short)f2bf(b.x); v[5] = (short)f2bf(b.y);
  v[6] = (short)f2bf(b.z); v[7] = (short)f2bf(b.w);
  return v;
}

#define PREP_B 256
#define NODEIN_B 313
#define H2_B 391
#define ZERO_B 128

// ================ combined pre-kernel: prep | node_in | h2 | zero (independent roles)
__global__ __launch_bounds__(256) void k_pre(const float* __restrict__ e2w,
                                             unsigned short* __restrict__ Af,
                                             const float* __restrict__ nfm,
                                             const float* __restrict__ mpw,
                                             const float* __restrict__ mpb,
                                             const float* __restrict__ e2b,
                                             float* __restrict__ outc,
                                             float* __restrict__ yc,
                                             const float* __restrict__ ea,
                                             const float* __restrict__ e1w,
                                             const float* __restrict__ e1b,
                                             unsigned short* __restrict__ h2,
                                             float* __restrict__ agg) {
  __shared__ float SH[9088];  // wS 4160 | eS 4160 | rows 4*192
  int bid = blockIdx.x, t = threadIdx.x;
  if (bid < PREP_B) {
    // ---- role: pre-swizzle e2_w into chunk-contiguous MFMA A-frag order
    int tid = bid * 256 + t;
    int l = tid & 63, kf = (tid >> 6) & 3, ct = tid >> 8;
    int gq = l >> 4, lm = l & 15;
    const float* src = e2w + (ct * 16 + lm) * 128 + kf * 32 + gq * 8;
    short8 v = pack8(*(const float4*)src, *(const float4*)(src + 4));
    *(short8*)((short*)Af + (size_t)tid * 8) = v;
    return;
  }
  bid -= PREP_B;
  if (bid < NODEIN_B) {
    // ---- role: out0 = relu(nf @ mp_w.T + mp_b); y0 = out0 @ e2bmat  (wave-autonomous)
    float* wS = SH;
    float* eS = SH + 4160;
    float* rows = SH + 8320;
    for (int idx = t; idx < 4096; idx += 256) {
      int o = idx >> 6, i = idx & 63;
      wS[i * 65 + o] = mpw[idx];           // mp_w[o][i]
      eS[i * 65 + o] = e2b[i * 64 + o];
    }
    __syncthreads();
    int w = t >> 6, o = t & 63;
    float* rx = rows + w * 192;
    float bo = mpb[o];
    for (int q = 0; q < 16; ++q) {
      int n = bid * 64 + w * 16 + q;
      if (n >= N_) break;
      rx[o] = nfm[(size_t)n * 64 + o];
      float acc = bo;
#pragma unroll
      for (int i4 = 0; i4 < 16; ++i4) {
        float4 xq = *(float4*)(rx + i4 * 4);
        acc += xq.x * wS[(i4 * 4 + 0) * 65 + o] + xq.y * wS[(i4 * 4 + 1) * 65 + o] +
               xq.z * wS[(i4 * 4 + 2) * 65 + o] + xq.w * wS[(i4 * 4 + 3) * 65 + o];
      }
      float m = fmaxf(acc, 0.f);
      outc[(size_t)n * 64 + o] = m;
      rx[64 + o] = m;
      float yv = 0.f;
#pragma unroll
      for (int j4 = 0; j4 < 16; ++j4) {
        float4 mq = *(float4*)(rx + 64 + j4 * 4);
        yv += mq.x * eS[(j4 * 4 + 0) * 65 + o] + mq.y * eS[(j4 * 4 + 1) * 65 + o] +
              mq.z * eS[(j4 * 4 + 2) * 65 + o] + mq.w * eS[(j4 * 4 + 3) * 65 + o];
      }
      yc[(size_t)n * 64 + o] = yv;
    }
    return;
  }
  bid -= NODEIN_B;
  if (bid < H2_B) {
    // ---- role: h2 = relu(edge_attr @ e1_w.T + e1_b), bf16 [E][128], via MFMA
    int w = t >> 6, l = t & 63, g = l >> 4, lm = l & 15;
    short8 bf[8];
#pragma unroll
    for (int cf = 0; cf < 8; ++cf) {
      int c = cf * 16 + lm;
      short8 v = {0, 0, 0, 0, 0, 0, 0, 0};
      if (g < 2) {
        const float4* wp = (const float4*)(e1w + c * 16 + g * 8);
        v = pack8(wp[0], wp[1]);
      } else if (g == 2) {
        v[0] = (short)f2bf(e1b[c]);
      }
      bf[cf] = v;
    }
    const f32x4 z = {0.f, 0.f, 0.f, 0.f};
    for (int tile = 0; tile < 4; ++tile) {
      int e0 = bid * 256 + tile * 64 + w * 16;
      if (e0 >= E_) break;
      int er = e0 + lm; if (er >= E_) er = E_ - 1;
      short8 a = {0, 0, 0, 0, 0, 0, 0, 0};
      if (g < 2) {
        const float4* ap = (const float4*)(ea + er * 16 + g * 8);
        a = pack8(ap[0], ap[1]);
      } else if (g == 2) {
        a[0] = (short)0x3F80;  // bf16(1.0)
      }
#pragma unroll
      for (int cf = 0; cf < 8; ++cf) {
        f32x4 acc = __builtin_amdgcn_mfma_f32_16x16x32_bf16(a, bf[cf], z, 0, 0, 0);
#pragma unroll
        for (int r = 0; r < 4; ++r) {
          int e = e0 + g * 4 + r;
          if (e < E_) h2[(size_t)e * 128 + cf * 16 + lm] = f2bf(fmaxf(acc[r], 0.f));
        }
      }
    }
    return;
  }
  bid -= H2_B;
  {
    // ---- role: zero agg (float4 grid-stride)
    float4* p = (float4*)agg;
    const float4 z4 = {0.f, 0.f, 0.f, 0.f};
    for (int idx = bid * 256 + t; idx < N_ * 16; idx += ZERO_B * 256) p[idx] = z4;
  }
}

// ================ K5: fused msgs + scatter. 128 edges/block, 4 waves.
// wave w = (op, kh): op=w>>1 owns oq {2op,2op+1}; kh=w&1 owns kf {2kh,2kh+1}.
// W streamed once per block, each frag read by exactly one wave; 1-iter prefetch.
__global__ __launch_bounds__(256, 3) void k_msgs(const float* __restrict__ x,
                                                 const float* __restrict__ y,
                                                 const unsigned short* __restrict__ h2,
                                                 const unsigned short* __restrict__ Af,
                                                 const int* __restrict__ ei,
                                                 float* __restrict__ agg) {
  __shared__ __align__(16) unsigned char POOL[33792];  // xg f32[64][132] | pm u16[2][128][66]
  __shared__ int sidx[128];
  __shared__ int didx[128];
  int t = threadIdx.x, w = t >> 6, l = t & 63;
  int op = w >> 1, kh = w & 1;
  int gq = l >> 4, lm = l & 15;
  int e0 = blockIdx.x * 128;
  if (t < 128) {
    int e = e0 + t;
    sidx[t] = (e < E_) ? ei[e] : 0;
    didx[t] = (e < E_) ? ei[E_ + e] : -1;
  }
  __syncthreads();  // sidx ready
  // hf: h2 frags for all 128 edges, this wave's 2 kf's
  int kb = 2 * kh;
  short8 hf[8][2];
#pragma unroll
  for (int ef = 0; ef < 8; ++ef) {
    int e = e0 + ef * 16 + lm;
    if (e >= E_) e = E_ - 1;
    const short8* hp = (const short8*)(h2 + (size_t)e * 128 + gq * 8);
    hf[ef][0] = hp[(kb + 0) * 4];
    hf[ef][1] = hp[(kb + 1) * 4];
  }
  // xg gather: f32 x^T [i][e], stride 132
  float* xg = (float*)POOL;
  {
    int e = t >> 1, h = t & 1;
    const float* xr = x + (size_t)sidx[e] * 64 + h * 32;
#pragma unroll
    for (int q = 0; q < 8; ++q) {
      float4 v = *(const float4*)(xr + q * 4);
      int ib = h * 32 + q * 4;
      xg[(ib + 0) * 132 + e] = v.x;
      xg[(ib + 1) * 132 + e] = v.y;
      xg[(ib + 2) * 132 + e] = v.z;
      xg[(ib + 3) * 132 + e] = v.w;
    }
  }
  __syncthreads();  // xg ready

  f32x4 macc[8][2];  // [ef][oql]
#pragma unroll
  for (int ef = 0; ef < 8; ++ef) {
    macc[ef][0] = f32x4{0.f, 0.f, 0.f, 0.f};
    macc[ef][1] = f32x4{0.f, 0.f, 0.f, 0.f};
  }
  const f32x4 z = {0.f, 0.f, 0.f, 0.f};
  const short8* As = (const short8*)Af;
  int fb = 2 * op;

  // prefetch i=0
  const short8* p0 = As + (size_t)((0 * 4 + fb) * 4 + kb) * 64 + l;
  short8 c00 = p0[0], c01 = p0[64], c10 = p0[256], c11 = p0[320];
  float xc[8];
#pragma unroll
  for (int ef = 0; ef < 8; ++ef) xc[ef] = xg[0 * 132 + ef * 16 + lm];

  for (int i = 0; i < 64; ++i) {
    int ip = (i + 1) & 63;  // wrap-around load on last iter (harmless)
    const short8* pn = As + (size_t)((ip * 4 + fb) * 4 + kb) * 64 + l;
    short8 n00 = pn[0], n01 = pn[64], n10 = pn[256], n11 = pn[320];
    float xn[8];
#pragma unroll
    for (int ef = 0; ef < 8; ++ef) xn[ef] = xg[ip * 132 + ef * 16 + lm];
#pragma unroll
    for (int ef = 0; ef < 8; ++ef) {
      f32x4 d0, d1;
      d0 = __builtin_amdgcn_mfma_f32_16x16x32_bf16(c00, hf[ef][0], z, 0, 0, 0);
      d1 = __builtin_amdgcn_mfma_f32_16x16x32_bf16(c10, hf[ef][0], z, 0, 0, 0);
      d0 = __builtin_amdgcn_mfma_f32_16x16x32_bf16(c01, hf[ef][1], d0, 0, 0, 0);
      d1 = __builtin_amdgcn_mfma_f32_16x16x32_bf16(c11, hf[ef][1], d1, 0, 0, 0);
      macc[ef][0] += xc[ef] * d0;
      macc[ef][1] += xc[ef] * d1;
    }
    c00 = n00; c01 = n01; c10 = n10; c11 = n11;
#pragma unroll
    for (int ef = 0; ef < 8; ++ef) xc[ef] = xn[ef];
  }
  __syncthreads();  // all waves done reading xg; POOL re-used as pm
  // pm: u16 [kh][e][o] stride 66; wave writes its (kh; o-range op*32..op*32+32)
  unsigned short* pm = (unsigned short*)POOL;
#pragma unroll
  for (int ef = 0; ef < 8; ++ef)
#pragma unroll
    for (int oql = 0; oql < 2; ++oql)
#pragma unroll
      for (int r = 0; r < 4; ++r)
        pm[kh * 8448 + (ef * 16 + lm) * 66 + op * 32 + oql * 16 + gq * 4 + r] =
            f2bf(macc[ef][oql][r]);
  __syncthreads();
  // reduce kh pairs + e2_b rank-1 term (y[src]) + scatter-add
  for (int it = 0; it < 32; ++it) {
    int idx = it * 256 + t;
    int e = idx >> 6, o = idx & 63;
    int d = didx[e];
    if (d >= 0) {
      float v = bf2f(pm[e * 66 + o]) + bf2f(pm[8448 + e * 66 + o]);
      v += y[(size_t)sidx[e] * 64 + o];
      atomicAdd(agg + (size_t)d * 64 + o, v);
    }
  }
}

// ================ K6: node update (+ re-zero agg), wave-autonomous, 64 nodes/block
__global__ __launch_bounds__(256) void k_update(const float* __restrict__ outc,
                                                float* __restrict__ agg,
                                                const float* __restrict__ root,
                                                const float* __restrict__ convb,
                                                const float* __restrict__ msgw,
                                                const float* __restrict__ msgb,
                                                const float* __restrict__ e2b,
                                                const float* __restrict__ nfm,
                                                int last,
                                                float* __restrict__ outn,
                                                float* __restrict__ yn,
                                                float* __restrict__ dout) {
  __shared__ float SH[17408];  // wS 8320 | rS 4160 | eS 4160 | rows 4*192
  float* wS = SH;
  float* rS = SH + 8320;
  float* eS = SH + 12480;
  float* rows = SH + 16640;
  int t = threadIdx.x;
  for (int idx = t; idx < 8192; idx += 256) {
    int o = idx >> 7, j = idx & 127;
    wS[j * 65 + o] = msgw[idx];  // msg_w[o][j]
  }
  for (int idx = t; idx < 4096; idx += 256) {
    int i = idx >> 6, o = idx & 63;
    rS[i * 65 + o] = root[idx];
    eS[i * 65 + o] = e2b[idx];
  }
  __syncthreads();
  int w = t >> 6, o = t & 63;
  float* rx = rows + w * 192;
  float cb = convb[o], mb = msgb[o];
  for (int q = 0; q < 16; ++q) {
    int n = blockIdx.x * 64 + w * 16 + q;
    if (n >= N_) break;
    rx[o] = outc[(size_t)n * 64 + o];
    float acc = agg[(size_t)n * 64 + o] + cb;
    agg[(size_t)n * 64 + o] = 0.f;
#pragma unroll
    for (int i4 = 0; i4 < 16; ++i4) {
      float4 xq = *(float4*)(rx + i4 * 4);
      acc += xq.x * rS[(i4 * 4 + 0) * 65 + o] + xq.y * rS[(i4 * 4 + 1) * 65 + o] +
             xq.z * rS[(i4 * 4 + 2) * 65 + o] + xq.w * rS[(i4 * 4 + 3) * 65 + o];
    }
    float m = fmaxf(acc, 0.f);
    rx[64 + o] = m;
    float o2 = mb;
#pragma unroll
    for (int j4 = 0; j4 < 16; ++j4) {
      float4 mq = *(float4*)(rx + 64 + j4 * 4);
      float4 xq = *(float4*)(rx + j4 * 4);
      o2 += mq.x * wS[(j4 * 4 + 0) * 65 + o] + mq.y * wS[(j4 * 4 + 1) * 65 + o] +
            mq.z * wS[(j4 * 4 + 2) * 65 + o] + mq.w * wS[(j4 * 4 + 3) * 65 + o];
      o2 += xq.x * wS[(64 + j4 * 4 + 0) * 65 + o] + xq.y * wS[(64 + j4 * 4 + 1) * 65 + o] +
            xq.z * wS[(64 + j4 * 4 + 2) * 65 + o] + xq.w * wS[(64 + j4 * 4 + 3) * 65 + o];
    }
    if (last) {
      dout[(size_t)n * 64 + o] = o2 + nfm[(size_t)n * 64 + o];
    } else {
      rx[128 + o] = o2;
      float yv = 0.f;
#pragma unroll
      for (int j4 = 0; j4 < 16; ++j4) {
        float4 nq = *(float4*)(rx + 128 + j4 * 4);
        yv += nq.x * eS[(j4 * 4 + 0) * 65 + o] + nq.y * eS[(j4 * 4 + 1) * 65 + o] +
              nq.z * eS[(j4 * 4 + 2) * 65 + o] + nq.w * eS[(j4 * 4 + 3) * 65 + o];
      }
      outn[(size_t)n * 64 + o] = o2;
      yn[(size_t)n * 64 + o] = yv;
    }
  }
}

extern "C" void kernel_launch(void* const* d_in, const int* in_sizes, int n_in,
                              void* d_out, int out_size, void* d_ws, size_t ws_size,
                              hipStream_t stream) {
  const float* nfm  = (const float*)d_in[0];
  const float* ea   = (const float*)d_in[1];
  const int*   ei   = (const int*)d_in[2];
  const float* mpw  = (const float*)d_in[3];
  const float* mpb  = (const float*)d_in[4];
  const float* msgw = (const float*)d_in[5];
  const float* msgb = (const float*)d_in[6];
  const float* e1w  = (const float*)d_in[7];
  const float* e1b  = (const float*)d_in[8];
  const float* e2w  = (const float*)d_in[9];
  const float* e2b  = (const float*)d_in[10];
  const float* root = (const float*)d_in[11];
  const float* convb= (const float*)d_in[12];
  float* out = (float*)d_out;

  char* ws = (char*)d_ws;
  unsigned short* h2 = (unsigned short*)ws; ws += (size_t)E_ * 128 * 2;
  unsigned short* Af = (unsigned short*)ws; ws += (size_t)4096 * 128 * 2;
  float* outa = (float*)ws; ws += (size_t)N_ * 64 * 4;
  float* ya   = (float*)ws; ws += (size_t)N_ * 64 * 4;
  float* outb = (float*)ws; ws += (size_t)N_ * 64 * 4;
  float* yb   = (float*)ws; ws += (size_t)N_ * 64 * 4;
  float* agg  = (float*)ws; ws += (size_t)N_ * 64 * 4;

  hipLaunchKernelGGL(k_pre, dim3(PREP_B + NODEIN_B + H2_B + ZERO_B), dim3(256), 0, stream,
                     e2w, Af, nfm, mpw, mpb, e2b, outa, ya, ea, e1w, e1b, h2, agg);

  float* oc = outa; float* yc = ya; float* on = outb; float* yv = yb;
  for (int s = 0; s < 3; ++s) {
    hipLaunchKernelGGL(k_msgs, dim3((E_ + 127) / 128), dim3(256), 0, stream, oc, yc, h2, Af, ei, agg);
    hipLaunchKernelGGL(k_update, dim3((N_ + 63) / 64), dim3(256), 0, stream, oc, agg, root, convb,
                       msgw, msgb, e2b, nfm, (s == 2) ? 1 : 0, on, yv, out);
    float* tp;
    tp = oc; oc = on; on = tp;
    tp = yc; yc = yv; yv = tp;
  }
}